// Round 1
// baseline (238.431 us; speedup 1.0000x reference)
//
#include <hip/hip_runtime.h>
#include <hip/hip_bf16.h>

// Problem constants
#define BB 8
#define QQ 128
#define KK 1024
#define DD 256
#define HH 256

// qp2/kp2 are pre-scaled by 2*log2(e) so tanh(q+k) = 1 - 2/(exp2(qp2+kp2)+1)
#define TWO_LOG2E 2.8853900817779268f
#define LOG2E     1.4426950408889634f

// ---------------------------------------------------------------------------
// K1: row-projection GEMM. out[r][h] = TWO_LOG2E * sum_d A[r][d]*W[h][d]
// Tile: 64 rows x 64 h per block, 256 threads, thread = 4 rows x 4 h.
// ---------------------------------------------------------------------------
__global__ __launch_bounds__(256) void proj_kernel(const float* __restrict__ A,
                                                   const float* __restrict__ W,
                                                   float* __restrict__ out) {
    __shared__ float As[64][68];  // pad 68: 2-way bank pattern (free)
    __shared__ float Ws[64][68];
    const int t  = threadIdx.x;
    const int tr = t & 15;        // row group: rows {tr+16i}
    const int th = t >> 4;        // h group:   hs   {th+16i}
    const int r0 = blockIdx.x * 64;
    const int h0 = blockIdx.y * 64;

    float acc[4][4] = {};

    for (int dc = 0; dc < DD; dc += 64) {
#pragma unroll
        for (int i = 0; i < 4; ++i) {
            int fi  = t + 256 * i;        // 0..1023 float4 slots
            int row = fi >> 4;            // 0..63
            int c4  = (fi & 15) << 2;     // 0..60
            *(float4*)&As[row][c4] = *(const float4*)&A[(size_t)(r0 + row) * DD + dc + c4];
            *(float4*)&Ws[row][c4] = *(const float4*)&W[(size_t)(h0 + row) * DD + dc + c4];
        }
        __syncthreads();
#pragma unroll 4
        for (int dd = 0; dd < 64; dd += 4) {
            float4 a4[4], w4[4];
#pragma unroll
            for (int i = 0; i < 4; ++i) a4[i] = *(float4*)&As[tr + 16 * i][dd];
#pragma unroll
            for (int i = 0; i < 4; ++i) w4[i] = *(float4*)&Ws[th + 16 * i][dd];
#pragma unroll
            for (int ri = 0; ri < 4; ++ri)
#pragma unroll
                for (int hi = 0; hi < 4; ++hi) {
                    acc[ri][hi] += a4[ri].x * w4[hi].x + a4[ri].y * w4[hi].y +
                                   a4[ri].z * w4[hi].z + a4[ri].w * w4[hi].w;
                }
        }
        __syncthreads();
    }
#pragma unroll
    for (int ri = 0; ri < 4; ++ri)
#pragma unroll
        for (int hi = 0; hi < 4; ++hi) {
            out[(size_t)(r0 + tr + 16 * ri) * HH + h0 + th + 16 * hi] =
                TWO_LOG2E * acc[ri][hi];
        }
}

// ---------------------------------------------------------------------------
// K2: scores[b][q][k] = sum_h w_v[h] * tanh(qp[b,q,h] + kp[b,k,h])
//   tanh via 1 - 2*rcp(exp2(qp2+kp2)+1); score = sw - 2*acc
// Tile: 32 q x 64 k per block (for one b); thread = 2 q x 4 k; h chunked by 64.
// ---------------------------------------------------------------------------
__global__ __launch_bounds__(256) void score_kernel(const float* __restrict__ qp2,
                                                    const float* __restrict__ kp2,
                                                    const float* __restrict__ wv,
                                                    float* __restrict__ scores) {
    __shared__ float qs[32][68];
    __shared__ float ks[64][68];
    __shared__ float ws[64];
    const int t  = threadIdx.x;
    const int kk = t & 15;   // k's = {kk+16j}
    const int qq = t >> 4;   // q's = {qq+16i}
    const int b  = blockIdx.z;
    const int q0 = blockIdx.y * 32;
    const int k0 = blockIdx.x * 64;

    const float* qpB = qp2 + ((size_t)b * QQ + q0) * HH;
    const float* kpB = kp2 + ((size_t)b * KK + k0) * HH;

    float acc[2][4] = {};
    float sw = 0.f;

    for (int hc = 0; hc < HH; hc += 64) {
#pragma unroll
        for (int i = 0; i < 2; ++i) {
            int fi = t + 256 * i; int row = fi >> 4; int c4 = (fi & 15) << 2;
            *(float4*)&qs[row][c4] = *(const float4*)&qpB[(size_t)row * HH + hc + c4];
        }
#pragma unroll
        for (int i = 0; i < 4; ++i) {
            int fi = t + 256 * i; int row = fi >> 4; int c4 = (fi & 15) << 2;
            *(float4*)&ks[row][c4] = *(const float4*)&kpB[(size_t)row * HH + hc + c4];
        }
        if (t < 16) *(float4*)&ws[t * 4] = *(const float4*)&wv[hc + t * 4];
        __syncthreads();

#pragma unroll 2
        for (int hh = 0; hh < 64; hh += 4) {
            float4 w4 = *(float4*)&ws[hh];
            const float* wa = (const float*)&w4;
            float4 q4[2], k4[4];
#pragma unroll
            for (int i = 0; i < 2; ++i) q4[i] = *(float4*)&qs[qq + 16 * i][hh];
#pragma unroll
            for (int j = 0; j < 4; ++j) k4[j] = *(float4*)&ks[kk + 16 * j][hh];
#pragma unroll
            for (int i = 0; i < 2; ++i) {
                const float* qa = (const float*)&q4[i];
#pragma unroll
                for (int j = 0; j < 4; ++j) {
                    const float* ka = (const float*)&k4[j];
#pragma unroll
                    for (int c = 0; c < 4; ++c) {
                        float x2 = qa[c] + ka[c];                      // 2x*log2e
                        float tt = __builtin_amdgcn_exp2f(x2);         // e^{2x}
                        acc[i][j] += wa[c] * __builtin_amdgcn_rcpf(tt + 1.0f);
                    }
                }
            }
            sw += w4.x + w4.y + w4.z + w4.w;
        }
        __syncthreads();
    }

#pragma unroll
    for (int i = 0; i < 2; ++i)
#pragma unroll
        for (int j = 0; j < 4; ++j) {
            int q = q0 + qq + 16 * i;
            int k = k0 + kk + 16 * j;
            scores[((size_t)b * QQ + q) * KK + k] = sw - 2.f * acc[i][j];
        }
}

// ---------------------------------------------------------------------------
// K3: masked softmax over K, in place. One block per (b,q), 256 threads x 4 k.
// ---------------------------------------------------------------------------
__global__ __launch_bounds__(256) void softmax_kernel(float* __restrict__ scores,
                                                      const int* __restrict__ vlen) {
    const int q = blockIdx.x, b = blockIdx.y;
    float* row = scores + ((size_t)b * QQ + q) * KK;
    const int t  = threadIdx.x;
    const int vl = vlen[b];
    const int k  = t * 4;

    float4 s = *(float4*)&row[k];
    s.x = (k + 0 < vl) ? s.x : -1e9f;
    s.y = (k + 1 < vl) ? s.y : -1e9f;
    s.z = (k + 2 < vl) ? s.z : -1e9f;
    s.w = (k + 3 < vl) ? s.w : -1e9f;

    float m = fmaxf(fmaxf(s.x, s.y), fmaxf(s.z, s.w));
#pragma unroll
    for (int off = 32; off; off >>= 1) m = fmaxf(m, __shfl_xor(m, off));

    __shared__ float redm[4], redsum[4];
    const int wave = t >> 6;
    if ((t & 63) == 0) redm[wave] = m;
    __syncthreads();
    m = fmaxf(fmaxf(redm[0], redm[1]), fmaxf(redm[2], redm[3]));

    float4 e;
    e.x = __builtin_amdgcn_exp2f((s.x - m) * LOG2E);
    e.y = __builtin_amdgcn_exp2f((s.y - m) * LOG2E);
    e.z = __builtin_amdgcn_exp2f((s.z - m) * LOG2E);
    e.w = __builtin_amdgcn_exp2f((s.w - m) * LOG2E);

    float sum = e.x + e.y + e.z + e.w;
#pragma unroll
    for (int off = 32; off; off >>= 1) sum += __shfl_xor(sum, off);
    if ((t & 63) == 0) redsum[wave] = sum;
    __syncthreads();
    sum = redsum[0] + redsum[1] + redsum[2] + redsum[3];

    const float inv = 1.0f / sum;
    e.x *= inv; e.y *= inv; e.z *= inv; e.w *= inv;
    *(float4*)&row[k] = e;
}

// ---------------------------------------------------------------------------
// K4: out[b][q][d] = sum_k attn[b][q][k] * V[b][k][d]
// Tile: 16 q x 64 d per block; 256 thr = 64 d-lanes x 4 k-slices; acc[16 q].
// ---------------------------------------------------------------------------
__global__ __launch_bounds__(256) void av_kernel(const float* __restrict__ attn,
                                                 const float* __restrict__ V,
                                                 float* __restrict__ out) {
    __shared__ float a_s[128][20];       // [k][q], pad 20 keeps 16B-aligned rows
    __shared__ float red[4][16][64];
    const int t  = threadIdx.x;
    const int td = t & 63;               // d lane
    const int tk = t >> 6;               // k slice 0..3
    const int b  = blockIdx.z;
    const int q0 = blockIdx.y * 16;
    const int d0 = blockIdx.x * 64;

    const float* attnB = attn + ((size_t)b * QQ + q0) * KK;
    const float* VB    = V + (size_t)b * KK * DD + d0;

    float acc[16] = {};

    for (int kc = 0; kc < KK; kc += 128) {
#pragma unroll
        for (int i = 0; i < 8; ++i) {
            int fi = t + 256 * i;            // 0..2047
            int qi = fi >> 7;                // 0..15
            int kx = fi & 127;               // 0..127
            a_s[kx][qi] = attnB[(size_t)qi * KK + kc + kx];
        }
        __syncthreads();
#pragma unroll 4
        for (int kk0 = 0; kk0 < 128; kk0 += 4) {
            int k = kk0 + tk;
            float v = VB[(size_t)(kc + k) * DD + td];
            float4 a0 = *(float4*)&a_s[k][0];
            float4 a1 = *(float4*)&a_s[k][4];
            float4 a2 = *(float4*)&a_s[k][8];
            float4 a3 = *(float4*)&a_s[k][12];
            acc[0]  += a0.x * v;  acc[1]  += a0.y * v;
            acc[2]  += a0.z * v;  acc[3]  += a0.w * v;
            acc[4]  += a1.x * v;  acc[5]  += a1.y * v;
            acc[6]  += a1.z * v;  acc[7]  += a1.w * v;
            acc[8]  += a2.x * v;  acc[9]  += a2.y * v;
            acc[10] += a2.z * v;  acc[11] += a2.w * v;
            acc[12] += a3.x * v;  acc[13] += a3.y * v;
            acc[14] += a3.z * v;  acc[15] += a3.w * v;
        }
        __syncthreads();
    }

#pragma unroll
    for (int qi = 0; qi < 16; ++qi) red[tk][qi][td] = acc[qi];
    __syncthreads();
#pragma unroll
    for (int j = 0; j < 4; ++j) {
        int qi = tk * 4 + j;
        float s = red[0][qi][td] + red[1][qi][td] + red[2][qi][td] + red[3][qi][td];
        out[((size_t)b * QQ + q0 + qi) * DD + d0 + td] = s;
    }
}

// ---------------------------------------------------------------------------
extern "C" void kernel_launch(void* const* d_in, const int* in_sizes, int n_in,
                              void* d_out, int out_size, void* d_ws, size_t ws_size,
                              hipStream_t stream) {
    const float* queries = (const float*)d_in[0];   // [B,Q,D]
    const float* keys    = (const float*)d_in[1];   // [B,K,D]
    const float* values  = (const float*)d_in[2];   // [B,K,D]
    const float* W_q     = (const float*)d_in[3];   // [H,D]
    const float* W_k     = (const float*)d_in[4];   // [H,D]
    const float* w_v     = (const float*)d_in[5];   // [H]
    const int*   vlen    = (const int*)d_in[6];     // [B]
    float* out = (float*)d_out;

    float* ws     = (float*)d_ws;
    float* qp2    = ws;                                   // B*Q*H = 262144
    float* kp2    = ws + (size_t)BB * QQ * HH;            // B*K*H = 2097152
    float* scores = kp2 + (size_t)BB * KK * HH;           // B*Q*K = 1048576

    // Projections (rows flattened over batch)
    proj_kernel<<<dim3(BB * QQ / 64, HH / 64, 1), 256, 0, stream>>>(queries, W_q, qp2);
    proj_kernel<<<dim3(BB * KK / 64, HH / 64, 1), 256, 0, stream>>>(keys, W_k, kp2);

    // Scores (the 268M-tanh kernel)
    score_kernel<<<dim3(KK / 64, QQ / 32, BB), 256, 0, stream>>>(qp2, kp2, w_v, scores);

    // Masked softmax in place
    softmax_kernel<<<dim3(QQ, BB, 1), 256, 0, stream>>>(scores, vlen);

    // attn @ V
    av_kernel<<<dim3(DD / 64, QQ / 16, BB), 256, 0, stream>>>(scores, values, out);
}

// Round 2
// 190.767 us; speedup vs baseline: 1.2499x; 1.2499x over previous
//
#include <hip/hip_runtime.h>
#include <hip/hip_bf16.h>

// Problem constants
#define BB 8
#define QQ 128
#define KK 1024
#define DD 256
#define HH 256

// A·V split-K config
#define KSPLIT 8
#define KCH (KK / KSPLIT)   // 128
#define QT 8                // q rows per av block

// qp2/kp2 are pre-scaled by 2*log2(e) so tanh(q+k) = 1 - 2/(exp2(qp2+kp2)+1)
#define TWO_LOG2E 2.8853900817779268f
#define LOG2E     1.4426950408889634f

// ---------------------------------------------------------------------------
// K1: row-projection GEMM. out[r][h] = TWO_LOG2E * sum_d A[r][d]*W[h][d]
// Tile: 64 rows x 64 h per block, 256 threads, thread = 4 rows x 4 h.
// ---------------------------------------------------------------------------
__global__ __launch_bounds__(256) void proj_kernel(const float* __restrict__ A,
                                                   const float* __restrict__ W,
                                                   float* __restrict__ out) {
    __shared__ float As[64][68];  // pad 68: 2-way bank pattern (free)
    __shared__ float Ws[64][68];
    const int t  = threadIdx.x;
    const int tr = t & 15;        // row group: rows {tr+16i}
    const int th = t >> 4;        // h group:   hs   {th+16i}
    const int r0 = blockIdx.x * 64;
    const int h0 = blockIdx.y * 64;

    float acc[4][4] = {};

    for (int dc = 0; dc < DD; dc += 64) {
#pragma unroll
        for (int i = 0; i < 4; ++i) {
            int fi  = t + 256 * i;        // 0..1023 float4 slots
            int row = fi >> 4;            // 0..63
            int c4  = (fi & 15) << 2;     // 0..60
            *(float4*)&As[row][c4] = *(const float4*)&A[(size_t)(r0 + row) * DD + dc + c4];
            *(float4*)&Ws[row][c4] = *(const float4*)&W[(size_t)(h0 + row) * DD + dc + c4];
        }
        __syncthreads();
#pragma unroll 4
        for (int dd = 0; dd < 64; dd += 4) {
            float4 a4[4], w4[4];
#pragma unroll
            for (int i = 0; i < 4; ++i) a4[i] = *(float4*)&As[tr + 16 * i][dd];
#pragma unroll
            for (int i = 0; i < 4; ++i) w4[i] = *(float4*)&Ws[th + 16 * i][dd];
#pragma unroll
            for (int ri = 0; ri < 4; ++ri)
#pragma unroll
                for (int hi = 0; hi < 4; ++hi) {
                    acc[ri][hi] += a4[ri].x * w4[hi].x + a4[ri].y * w4[hi].y +
                                   a4[ri].z * w4[hi].z + a4[ri].w * w4[hi].w;
                }
        }
        __syncthreads();
    }
#pragma unroll
    for (int ri = 0; ri < 4; ++ri)
#pragma unroll
        for (int hi = 0; hi < 4; ++hi) {
            out[(size_t)(r0 + tr + 16 * ri) * HH + h0 + th + 16 * hi] =
                TWO_LOG2E * acc[ri][hi];
        }
}

// ---------------------------------------------------------------------------
// K2: scores[b][q][k] = sum_h w_v[h] * tanh(qp[b,q,h] + kp[b,k,h])
//   tanh via 1 - 2*rcp(exp2(qp2+kp2)+1); score = sw - 2*acc
// Tile: 32 q x 64 k per block (for one b); thread = 2 q x 4 k; h chunked by 64.
// ---------------------------------------------------------------------------
__global__ __launch_bounds__(256) void score_kernel(const float* __restrict__ qp2,
                                                    const float* __restrict__ kp2,
                                                    const float* __restrict__ wv,
                                                    float* __restrict__ scores) {
    __shared__ float qs[32][68];
    __shared__ float ks[64][68];
    __shared__ float ws[64];
    const int t  = threadIdx.x;
    const int kk = t & 15;   // k's = {kk+16j}
    const int qq = t >> 4;   // q's = {qq+16i}
    const int b  = blockIdx.z;
    const int q0 = blockIdx.y * 32;
    const int k0 = blockIdx.x * 64;

    const float* qpB = qp2 + ((size_t)b * QQ + q0) * HH;
    const float* kpB = kp2 + ((size_t)b * KK + k0) * HH;

    float acc[2][4] = {};
    float sw = 0.f;

    for (int hc = 0; hc < HH; hc += 64) {
#pragma unroll
        for (int i = 0; i < 2; ++i) {
            int fi = t + 256 * i; int row = fi >> 4; int c4 = (fi & 15) << 2;
            *(float4*)&qs[row][c4] = *(const float4*)&qpB[(size_t)row * HH + hc + c4];
        }
#pragma unroll
        for (int i = 0; i < 4; ++i) {
            int fi = t + 256 * i; int row = fi >> 4; int c4 = (fi & 15) << 2;
            *(float4*)&ks[row][c4] = *(const float4*)&kpB[(size_t)row * HH + hc + c4];
        }
        if (t < 16) *(float4*)&ws[t * 4] = *(const float4*)&wv[hc + t * 4];
        __syncthreads();

#pragma unroll 2
        for (int hh = 0; hh < 64; hh += 4) {
            float4 w4 = *(float4*)&ws[hh];
            const float* wa = (const float*)&w4;
            float4 q4[2], k4[4];
#pragma unroll
            for (int i = 0; i < 2; ++i) q4[i] = *(float4*)&qs[qq + 16 * i][hh];
#pragma unroll
            for (int j = 0; j < 4; ++j) k4[j] = *(float4*)&ks[kk + 16 * j][hh];
#pragma unroll
            for (int i = 0; i < 2; ++i) {
                const float* qa = (const float*)&q4[i];
#pragma unroll
                for (int j = 0; j < 4; ++j) {
                    const float* ka = (const float*)&k4[j];
#pragma unroll
                    for (int c = 0; c < 4; ++c) {
                        float x2 = qa[c] + ka[c];                      // 2x*log2e
                        float tt = __builtin_amdgcn_exp2f(x2);         // e^{2x}
                        acc[i][j] += wa[c] * __builtin_amdgcn_rcpf(tt + 1.0f);
                    }
                }
            }
            sw += w4.x + w4.y + w4.z + w4.w;
        }
        __syncthreads();
    }

#pragma unroll
    for (int i = 0; i < 2; ++i)
#pragma unroll
        for (int j = 0; j < 4; ++j) {
            int q = q0 + qq + 16 * i;
            int k = k0 + kk + 16 * j;
            scores[((size_t)b * QQ + q) * KK + k] = sw - 2.f * acc[i][j];
        }
}

// ---------------------------------------------------------------------------
// K3: masked softmax over K, in place. One block per (b,q), 256 threads x 4 k.
// ---------------------------------------------------------------------------
__global__ __launch_bounds__(256) void softmax_kernel(float* __restrict__ scores,
                                                      const int* __restrict__ vlen) {
    const int q = blockIdx.x, b = blockIdx.y;
    float* row = scores + ((size_t)b * QQ + q) * KK;
    const int t  = threadIdx.x;
    const int vl = vlen[b];
    const int k  = t * 4;

    float4 s = *(float4*)&row[k];
    s.x = (k + 0 < vl) ? s.x : -1e9f;
    s.y = (k + 1 < vl) ? s.y : -1e9f;
    s.z = (k + 2 < vl) ? s.z : -1e9f;
    s.w = (k + 3 < vl) ? s.w : -1e9f;

    float m = fmaxf(fmaxf(s.x, s.y), fmaxf(s.z, s.w));
#pragma unroll
    for (int off = 32; off; off >>= 1) m = fmaxf(m, __shfl_xor(m, off));

    __shared__ float redm[4], redsum[4];
    const int wave = t >> 6;
    if ((t & 63) == 0) redm[wave] = m;
    __syncthreads();
    m = fmaxf(fmaxf(redm[0], redm[1]), fmaxf(redm[2], redm[3]));

    float4 e;
    e.x = __builtin_amdgcn_exp2f((s.x - m) * LOG2E);
    e.y = __builtin_amdgcn_exp2f((s.y - m) * LOG2E);
    e.z = __builtin_amdgcn_exp2f((s.z - m) * LOG2E);
    e.w = __builtin_amdgcn_exp2f((s.w - m) * LOG2E);

    float sum = e.x + e.y + e.z + e.w;
#pragma unroll
    for (int off = 32; off; off >>= 1) sum += __shfl_xor(sum, off);
    if ((t & 63) == 0) redsum[wave] = sum;
    __syncthreads();
    sum = redsum[0] + redsum[1] + redsum[2] + redsum[3];

    const float inv = 1.0f / sum;
    e.x *= inv; e.y *= inv; e.z *= inv; e.w *= inv;
    *(float4*)&row[k] = e;
}

// ---------------------------------------------------------------------------
// K4a: split-K partial A·V.
// Block = (ks, q-tile of 8, b). 256 threads; thread t owns d-column t (full D).
// attn chunk (8 q x 128 k = 4 KB) staged in LDS; V rows loaded coalesced;
// inner loop: 4 independent V loads + 8 broadcast ds_read_b128 + 32 FMA.
// Grid 1024 blocks -> 4 blocks/CU, 16 waves/CU (vs 1 block/CU in R0's av).
// ---------------------------------------------------------------------------
__global__ __launch_bounds__(256) void av_partial(const float* __restrict__ attn,
                                                  const float* __restrict__ V,
                                                  float* __restrict__ partial) {
    __shared__ float a_s[QT][KCH];     // [8][128], rows contiguous
    const int t  = threadIdx.x;        // d index 0..255
    const int ks = blockIdx.x;         // k-chunk
    const int q0 = blockIdx.y * QT;
    const int b  = blockIdx.z;
    const int kc0 = ks * KCH;

    const float* attnB = attn + ((size_t)b * QQ + q0) * KK + kc0;
    const float* VB    = V + ((size_t)b * KK + kc0) * DD;

    // Stage attn chunk: 1024 floats = 256 float4, one per thread. Coalesced
    // global read; contiguous LDS write (conflict-free).
    {
        int qi = t >> 5;               // 0..7
        int k4 = t & 31;               // 0..31 float4 slots per row
        *(float4*)&a_s[qi][k4 * 4] = *(const float4*)&attnB[(size_t)qi * KK + k4 * 4];
    }
    __syncthreads();

    float acc[QT] = {};
#pragma unroll 2
    for (int kg = 0; kg < KCH; kg += 4) {
        float v0 = VB[(size_t)(kg + 0) * DD + t];
        float v1 = VB[(size_t)(kg + 1) * DD + t];
        float v2 = VB[(size_t)(kg + 2) * DD + t];
        float v3 = VB[(size_t)(kg + 3) * DD + t];
#pragma unroll
        for (int qi = 0; qi < QT; ++qi) {
            float4 a = *(float4*)&a_s[qi][kg];   // broadcast read (all lanes same addr)
            acc[qi] += a.x * v0 + a.y * v1 + a.z * v2 + a.w * v3;
        }
    }

#pragma unroll
    for (int qi = 0; qi < QT; ++qi) {
        partial[(size_t)ks * (BB * QQ * DD) +
                ((size_t)b * QQ + q0 + qi) * DD + t] = acc[qi];
    }
}

// ---------------------------------------------------------------------------
// K4b: reduce the KSPLIT partials into out. float4 per thread.
// ---------------------------------------------------------------------------
__global__ __launch_bounds__(256) void av_reduce(const float* __restrict__ partial,
                                                 float* __restrict__ out) {
    const int i = blockIdx.x * 256 + threadIdx.x;   // float4 index, 65536 total
    const float4* p4 = (const float4*)partial;
    const int stride4 = BB * QQ * DD / 4;           // 65536
    float4 s = p4[i];
#pragma unroll
    for (int ks = 1; ks < KSPLIT; ++ks) {
        float4 x = p4[(size_t)ks * stride4 + i];
        s.x += x.x; s.y += x.y; s.z += x.z; s.w += x.w;
    }
    ((float4*)out)[i] = s;
}

// ---------------------------------------------------------------------------
extern "C" void kernel_launch(void* const* d_in, const int* in_sizes, int n_in,
                              void* d_out, int out_size, void* d_ws, size_t ws_size,
                              hipStream_t stream) {
    const float* queries = (const float*)d_in[0];   // [B,Q,D]
    const float* keys    = (const float*)d_in[1];   // [B,K,D]
    const float* values  = (const float*)d_in[2];   // [B,K,D]
    const float* W_q     = (const float*)d_in[3];   // [H,D]
    const float* W_k     = (const float*)d_in[4];   // [H,D]
    const float* w_v     = (const float*)d_in[5];   // [H]
    const int*   vlen    = (const int*)d_in[6];     // [B]
    float* out = (float*)d_out;

    float* ws      = (float*)d_ws;
    float* qp2     = ws;                                   // B*Q*H = 262144
    float* kp2     = ws + (size_t)BB * QQ * HH;            // B*K*H = 2097152
    float* scores  = kp2 + (size_t)BB * KK * HH;           // B*Q*K = 1048576
    float* partial = scores + (size_t)BB * QQ * KK;        // KSPLIT*B*Q*D = 2097152

    // Projections (rows flattened over batch)
    proj_kernel<<<dim3(BB * QQ / 64, HH / 64, 1), 256, 0, stream>>>(queries, W_q, qp2);
    proj_kernel<<<dim3(BB * KK / 64, HH / 64, 1), 256, 0, stream>>>(keys, W_k, kp2);

    // Scores (the 268M-tanh kernel)
    score_kernel<<<dim3(KK / 64, QQ / 32, BB), 256, 0, stream>>>(qp2, kp2, w_v, scores);

    // Masked softmax in place
    softmax_kernel<<<dim3(QQ, BB, 1), 256, 0, stream>>>(scores, vlen);

    // attn @ V, split-K two-phase
    av_partial<<<dim3(KSPLIT, QQ / QT, BB), 256, 0, stream>>>(scores, values, partial);
    av_reduce<<<dim3(BB * QQ * DD / 4 / 256, 1, 1), 256, 0, stream>>>(partial, out);
}

// Round 3
// 156.329 us; speedup vs baseline: 1.5252x; 1.2203x over previous
//
#include <hip/hip_runtime.h>

// Problem constants
#define BB 8
#define QQ 128
#define KK 1024
#define DD 256
#define HH 256

// A·V split-K config
#define KSPLIT 8
#define KCH (KK / KSPLIT)   // 128
#define QT 8                // q rows per av block

#define TWO_LOG2E     2.8853900817779268f
#define NEG_TWO_LOG2E -2.8853900817779268f

// ---------------------------------------------------------------------------
// K1: fused Q+K projection. Global row r in [0, B*Q + B*K); rows < B*Q are
// queries (weights W_q), the rest are keys (W_k). Output (contiguous eq||ek):
//   eproj[r][h] = exp2( TWO_LOG2E * sum_d A[r][d] * W[h][d] )
// so the score kernel's exp2 moves here: 2.36M evals instead of 268M.
// Tile: 64 rows x 64 h, 256 threads, thread = 4 rows x 4 h.
// ---------------------------------------------------------------------------
__global__ __launch_bounds__(256) void proj_kernel(const float* __restrict__ queries,
                                                   const float* __restrict__ keys,
                                                   const float* __restrict__ Wq,
                                                   const float* __restrict__ Wk,
                                                   float* __restrict__ eproj) {
    __shared__ float As[64][68];  // pad 68: 2-way bank pattern (free)
    __shared__ float Ws[64][68];
    const int t  = threadIdx.x;
    const int tr = t & 15;        // row group: rows {tr+16i}
    const int th = t >> 4;        // h group:   hs   {th+16i}
    const int r0 = blockIdx.x * 64;               // global row base
    const int h0 = blockIdx.y * 64;
    const bool isQ = (r0 < BB * QQ);
    const float* A = isQ ? (queries + (size_t)r0 * DD)
                         : (keys + (size_t)(r0 - BB * QQ) * DD);
    const float* W = isQ ? Wq : Wk;

    float acc[4][4] = {};

    for (int dc = 0; dc < DD; dc += 64) {
#pragma unroll
        for (int i = 0; i < 4; ++i) {
            int fi  = t + 256 * i;        // 0..1023 float4 slots
            int row = fi >> 4;            // 0..63
            int c4  = (fi & 15) << 2;     // 0..60
            *(float4*)&As[row][c4] = *(const float4*)&A[(size_t)row * DD + dc + c4];
            *(float4*)&Ws[row][c4] = *(const float4*)&W[(size_t)(h0 + row) * DD + dc + c4];
        }
        __syncthreads();
#pragma unroll 4
        for (int dd = 0; dd < 64; dd += 4) {
            float4 a4[4], w4[4];
#pragma unroll
            for (int i = 0; i < 4; ++i) a4[i] = *(float4*)&As[tr + 16 * i][dd];
#pragma unroll
            for (int i = 0; i < 4; ++i) w4[i] = *(float4*)&Ws[th + 16 * i][dd];
#pragma unroll
            for (int ri = 0; ri < 4; ++ri)
#pragma unroll
                for (int hi = 0; hi < 4; ++hi) {
                    acc[ri][hi] += a4[ri].x * w4[hi].x + a4[ri].y * w4[hi].y +
                                   a4[ri].z * w4[hi].z + a4[ri].w * w4[hi].w;
                }
        }
        __syncthreads();
    }
#pragma unroll
    for (int ri = 0; ri < 4; ++ri)
#pragma unroll
        for (int hi = 0; hi < 4; ++hi) {
            eproj[(size_t)(r0 + tr + 16 * ri) * HH + h0 + th + 16 * hi] =
                __builtin_amdgcn_exp2f(TWO_LOG2E * acc[ri][hi]);
        }
}

// ---------------------------------------------------------------------------
// K2: unnormalized masked attention weights.
//   acc = sum_h w_v[h] * rcp(eq[b,q,h]*ek[b,k,h] + 1)       (2 full + 1 trans)
//   score' = -2*acc (the k-constant sum_h w_v shift cancels in softmax)
//   p = (k < vl) ? exp(score') : 0 ;  vl==0 -> p=1 (uniform row, matches ref)
// Tile: 32 q x 32 k per block, thread = 2q x 2k; grid 1024 blocks = 4/CU.
// ---------------------------------------------------------------------------
__global__ __launch_bounds__(256) void score_kernel(const float* __restrict__ eproj,
                                                    const float* __restrict__ wv,
                                                    const int* __restrict__ vlen,
                                                    float* __restrict__ p) {
    __shared__ float qs[32][68];
    __shared__ float ks_[32][68];
    __shared__ float ws[64];
    const int t  = threadIdx.x;
    const int tk = t & 15;   // k's = {tk, tk+16}
    const int tq = t >> 4;   // q's = {tq, tq+16}
    const int b  = blockIdx.z;
    const int q0 = blockIdx.y * 32;
    const int k0 = blockIdx.x * 32;

    const float* qpB = eproj + ((size_t)(b * QQ + q0)) * HH;
    const float* kpB = eproj + ((size_t)(BB * QQ + b * KK + k0)) * HH;

    float acc[2][2] = {};

    for (int hc = 0; hc < HH; hc += 64) {
#pragma unroll
        for (int i = 0; i < 2; ++i) {
            int fi = t + 256 * i; int row = fi >> 4; int c4 = (fi & 15) << 2;
            *(float4*)&qs[row][c4]  = *(const float4*)&qpB[(size_t)row * HH + hc + c4];
            *(float4*)&ks_[row][c4] = *(const float4*)&kpB[(size_t)row * HH + hc + c4];
        }
        if (t < 16) *(float4*)&ws[t * 4] = *(const float4*)&wv[hc + t * 4];
        __syncthreads();

#pragma unroll 4
        for (int hh = 0; hh < 64; hh += 4) {
            float4 w4 = *(float4*)&ws[hh];
            const float* wa = (const float*)&w4;
            float4 q4[2], k4[2];
            q4[0] = *(float4*)&qs[tq][hh];
            q4[1] = *(float4*)&qs[tq + 16][hh];
            k4[0] = *(float4*)&ks_[tk][hh];
            k4[1] = *(float4*)&ks_[tk + 16][hh];
#pragma unroll
            for (int i = 0; i < 2; ++i) {
                const float* qa = (const float*)&q4[i];
#pragma unroll
                for (int j = 0; j < 2; ++j) {
                    const float* ka = (const float*)&k4[j];
#pragma unroll
                    for (int c = 0; c < 4; ++c) {
                        float d = __builtin_fmaf(qa[c], ka[c], 1.0f);  // eq*ek+1
                        acc[i][j] += wa[c] * __builtin_amdgcn_rcpf(d);
                    }
                }
            }
        }
        __syncthreads();
    }

    const int vl = vlen[b];
#pragma unroll
    for (int i = 0; i < 2; ++i)
#pragma unroll
        for (int j = 0; j < 2; ++j) {
            int q = q0 + tq + 16 * i;
            int k = k0 + tk + 16 * j;
            float pv;
            if (vl == 0) pv = 1.0f;   // all-masked row -> uniform attn (ref behavior)
            else pv = (k < vl) ? __builtin_amdgcn_exp2f(NEG_TWO_LOG2E * acc[i][j])
                               : 0.0f;
            p[((size_t)b * QQ + q) * KK + k] = pv;
        }
}

// ---------------------------------------------------------------------------
// K3: split-K partial A·V on unnormalized p, plus per-chunk row sums.
// Block = (ks, q-tile of 8, b); thread t owns d-column t. 8-deep V prefetch.
// ---------------------------------------------------------------------------
__global__ __launch_bounds__(256) void av_partial(const float* __restrict__ p,
                                                  const float* __restrict__ V,
                                                  float* __restrict__ partial,
                                                  float* __restrict__ psum) {
    __shared__ float a_s[QT][KCH];     // [8][128]
    const int t   = threadIdx.x;       // d index 0..255
    const int ksb = blockIdx.x;        // k-chunk
    const int q0  = blockIdx.y * QT;
    const int b   = blockIdx.z;
    const int kc0 = ksb * KCH;

    const float* pB = p + ((size_t)b * QQ + q0) * KK + kc0;
    const float* VB = V + ((size_t)b * KK + kc0) * DD;

    {   // stage p chunk: 1024 floats = 256 float4, conflict-free
        int qi = t >> 5;
        int k4 = (t & 31) << 2;
        *(float4*)&a_s[qi][k4] = *(const float4*)&pB[(size_t)qi * KK + k4];
    }
    __syncthreads();

    // per-(b,q) chunk sum of p (for softmax denominator)
    if (t < QT) {
        float s = 0.f;
        for (int x = 0; x < KCH; x += 4) {
            float4 v = *(float4*)&a_s[t][x];
            s += v.x + v.y + v.z + v.w;
        }
        psum[((size_t)ksb * BB + b) * QQ + q0 + t] = s;
    }

    float acc[QT] = {};
    float vc[8], vn[8];
#pragma unroll
    for (int j = 0; j < 8; ++j) vc[j] = VB[(size_t)j * DD + t];

    for (int kg = 0; kg < KCH; kg += 8) {
        if (kg + 8 < KCH) {
#pragma unroll
            for (int j = 0; j < 8; ++j) vn[j] = VB[(size_t)(kg + 8 + j) * DD + t];
        }
#pragma unroll
        for (int qi = 0; qi < QT; ++qi) {
            float4 a0 = *(float4*)&a_s[qi][kg];       // broadcast reads (bank-cheap)
            float4 a1 = *(float4*)&a_s[qi][kg + 4];
            acc[qi] += a0.x * vc[0] + a0.y * vc[1] + a0.z * vc[2] + a0.w * vc[3] +
                       a1.x * vc[4] + a1.y * vc[5] + a1.z * vc[6] + a1.w * vc[7];
        }
#pragma unroll
        for (int j = 0; j < 8; ++j) vc[j] = vn[j];
    }

#pragma unroll
    for (int qi = 0; qi < QT; ++qi) {
        partial[(size_t)ksb * (BB * QQ * DD) +
                ((size_t)b * QQ + q0 + qi) * DD + t] = acc[qi];
    }
}

// ---------------------------------------------------------------------------
// K4: reduce partials and normalize by the row sum S. float4 per thread.
// ---------------------------------------------------------------------------
__global__ __launch_bounds__(256) void av_reduce(const float* __restrict__ partial,
                                                 const float* __restrict__ psum,
                                                 float* __restrict__ out) {
    const int i  = blockIdx.x * 256 + threadIdx.x;   // float4 index, 65536 total
    const int bq = i >> 6;                           // / (DD/4)

    float S = 0.f;
#pragma unroll
    for (int ks = 0; ks < KSPLIT; ++ks) S += psum[(size_t)ks * (BB * QQ) + bq];

    const float4* p4 = (const float4*)partial;
    const int stride4 = BB * QQ * DD / 4;            // 65536
    float4 s = p4[i];
#pragma unroll
    for (int ks = 1; ks < KSPLIT; ++ks) {
        float4 x = p4[(size_t)ks * stride4 + i];
        s.x += x.x; s.y += x.y; s.z += x.z; s.w += x.w;
    }
    const float inv = 1.0f / S;   // S>0 always: p>=8e-12 unmasked, vl==0 -> p=1
    s.x *= inv; s.y *= inv; s.z *= inv; s.w *= inv;
    ((float4*)out)[i] = s;
}

// ---------------------------------------------------------------------------
extern "C" void kernel_launch(void* const* d_in, const int* in_sizes, int n_in,
                              void* d_out, int out_size, void* d_ws, size_t ws_size,
                              hipStream_t stream) {
    const float* queries = (const float*)d_in[0];   // [B,Q,D]
    const float* keys    = (const float*)d_in[1];   // [B,K,D]
    const float* values  = (const float*)d_in[2];   // [B,K,D]
    const float* W_q     = (const float*)d_in[3];   // [H,D]
    const float* W_k     = (const float*)d_in[4];   // [H,D]
    const float* w_v     = (const float*)d_in[5];   // [H]
    const int*   vlen    = (const int*)d_in[6];     // [B]
    float* out = (float*)d_out;

    float* ws    = (float*)d_ws;
    float* eproj = ws;                                      // (B*Q + B*K)*H = 2359296
    float* p     = ws + (size_t)(BB * QQ + BB * KK) * HH;   // B*Q*K = 1048576
    float* psum  = p + (size_t)BB * QQ * KK;                // KSPLIT*B*Q = 8192
    // partial aliases eproj (dead after score_kernel): KSPLIT*B*Q*D = 2097152 fits
    float* partial = ws;

    // Fused Q+K projection with exp2 epilogue
    proj_kernel<<<dim3((BB * QQ + BB * KK) / 64, HH / 64, 1), 256, 0, stream>>>(
        queries, keys, W_q, W_k, eproj);

    // Unnormalized masked attention weights (1 trans/term inner loop)
    score_kernel<<<dim3(KK / 32, QQ / 32, BB), 256, 0, stream>>>(eproj, w_v, vlen, p);

    // p @ V split-K + chunk row sums
    av_partial<<<dim3(KSPLIT, QQ / QT, BB), 256, 0, stream>>>(p, values, partial, psum);

    // Reduce + softmax normalization
    av_reduce<<<dim3(BB * QQ * DD / 4 / 256, 1, 1), 256, 0, stream>>>(partial, psum, out);
}